// Round 16
// baseline (445.557 us; speedup 1.0000x reference)
//
#include <hip/hip_runtime.h>
#include <hip/hip_bf16.h>

#define HID 128
#define FDIM 133

typedef __hip_bfloat16 bf16;
typedef unsigned short u16;
typedef __attribute__((ext_vector_type(8))) short short8;
typedef __attribute__((ext_vector_type(4))) float v4f;

__device__ __forceinline__ u16 bbits(float v) {
    union { bf16 b; u16 u; } cv; cv.b = __float2bfloat16(v); return cv.u;
}
__device__ __forceinline__ float lo16(unsigned u) { return __uint_as_float(u << 16); }
__device__ __forceinline__ float hi16(unsigned u) { return __uint_as_float(u & 0xffff0000u); }
__device__ __forceinline__ float u2f(u16 u) { return __uint_as_float((unsigned)u << 16); }
__device__ __forceinline__ unsigned pksub(unsigned a, unsigned b) {
    float lo = lo16(a) - lo16(b);
    float hi = hi16(a) - hi16(b);
    return (unsigned)bbits(lo) | ((unsigned)bbits(hi) << 16);
}
__device__ __forceinline__ unsigned paddrelu(unsigned a, unsigned b) {
    float lo = fmaxf(lo16(a) + lo16(b), 0.f);
    float hi = fmaxf(hi16(a) + hi16(b), 0.f);
    return (unsigned)bbits(lo) | ((unsigned)bbits(hi) << 16);
}

__global__ void k_zero(float* __restrict__ p, long long n) {
    long long i = (long long)blockIdx.x * blockDim.x + threadIdx.x;
    long long st = (long long)gridDim.x * blockDim.x;
    for (; i < n; i += st) p[i] = 0.f;
}

// xb[n][136] = bf16(x[n][0..132]), 0 pad for 133..135
__global__ void k_cast(const float* __restrict__ x, u16* __restrict__ xb, int N) {
    int i = blockIdx.x * blockDim.x + threadIdx.x;
    int st = gridDim.x * blockDim.x;
    int total = N * 136;
    for (; i < total; i += st) {
        int n = i / 136, k = i - n * 136;
        float v = (k < FDIM) ? x[(size_t)n * FDIM + k] : 0.f;
        xb[i] = bbits(v);
    }
}

// ---------------- CSR build (incoming edges per dst) ----------------
__global__ void k_hist(const int* __restrict__ dst, int* __restrict__ deg, int E) {
    int i = blockIdx.x * blockDim.x + threadIdx.x;
    if (i < E) atomicAdd(&deg[dst[i]], 1);
}

__global__ void k_scanA(const int* __restrict__ deg, int* __restrict__ offs,
                        int* __restrict__ bsum, int N) {
    __shared__ int sh[256];
    int t = threadIdx.x;
    int base = blockIdx.x * 1024 + t * 4;
    int d0 = (base + 0 < N) ? deg[base + 0] : 0;
    int d1 = (base + 1 < N) ? deg[base + 1] : 0;
    int d2 = (base + 2 < N) ? deg[base + 2] : 0;
    int d3 = (base + 3 < N) ? deg[base + 3] : 0;
    sh[t] = d0 + d1 + d2 + d3;
    __syncthreads();
    for (int off = 1; off < 256; off <<= 1) {
        int v = (t >= off) ? sh[t - off] : 0;
        __syncthreads();
        sh[t] += v;
        __syncthreads();
    }
    int o = (t > 0) ? sh[t - 1] : 0;
    if (t == 255) bsum[blockIdx.x] = sh[255];
    if (base + 0 < N) offs[base + 0] = o; o += d0;
    if (base + 1 < N) offs[base + 1] = o; o += d1;
    if (base + 2 < N) offs[base + 2] = o; o += d2;
    if (base + 3 < N) offs[base + 3] = o;
}

__global__ void k_scanB(int* __restrict__ bsum, int nb) {
    __shared__ int sh[256];
    int t = threadIdx.x;
    sh[t] = (t < nb) ? bsum[t] : 0;
    __syncthreads();
    for (int off = 1; off < 256; off <<= 1) {
        int v = (t >= off) ? sh[t - off] : 0;
        __syncthreads();
        sh[t] += v;
        __syncthreads();
    }
    if (t < nb) bsum[t] = (t > 0) ? sh[t - 1] : 0;
}

__global__ void k_scanC(int* __restrict__ offs, const int* __restrict__ bsum, int N) {
    int i = blockIdx.x * blockDim.x + threadIdx.x;
    if (i < N) offs[i] += bsum[i >> 10];
}

__global__ void k_fill(const int* __restrict__ dst, const int* __restrict__ offs,
                       int* __restrict__ cursor, int* __restrict__ csr, int E) {
    int e = blockIdx.x * blockDim.x + threadIdx.x;
    if (e < E) {
        int d = dst[e];
        int p = offs[d] + atomicAdd(&cursor[d], 1);
        csr[p] = e;
    }
}

// starts[g] = lower_bound(batch, g) for g in [0, G]  (batch sorted)
__global__ void k_starts(const int* __restrict__ batch, int* __restrict__ starts,
                         int N, int G) {
    int g = blockIdx.x * blockDim.x + threadIdx.x;
    if (g > G) return;
    int lo = 0, hi = N;
    while (lo < hi) { int mid = (lo + hi) >> 1; if (batch[mid] < g) lo = mid + 1; else hi = mid; }
    starts[g] = lo;
}

// mnb[n] (bf16) = sum of h rows over incoming edges.
// Half-wave pairing: lanes 0-31 even-slot edges, lanes 32-63 odd-slot; each
// lane loads uint2 (8 B = 4 channels). Cross-half combine via shfl_xor.
__global__ void k_gather(const u16* __restrict__ h, const int* __restrict__ csr,
                         const int* __restrict__ offs, const int* __restrict__ deg,
                         u16* __restrict__ mnb, int N) {
    int gw = (blockIdx.x * blockDim.x + threadIdx.x) >> 6;
    int lane = threadIdx.x & 63;
    int nw = (gridDim.x * blockDim.x) >> 6;
    const int half = lane >> 5;
    const int cl = lane & 31;
    for (int n = gw; n < N; n += nw) {
        int s = offs[n], d = deg[n];
        float a0 = 0.f, a1 = 0.f, a2 = 0.f, a3 = 0.f;
        int i = 0;
        while (i < d) {
            int ei[4];
            uint2 uu[4];
#pragma unroll
            for (int k = 0; k < 4; ++k) {
                int j = i + 2 * k + half;
                ei[k] = (j < d) ? csr[s + j] : -1;
            }
#pragma unroll
            for (int k = 0; k < 4; ++k)
                uu[k] = (ei[k] >= 0)
                    ? *reinterpret_cast<const uint2*>(h + (size_t)ei[k] * HID + cl * 4)
                    : make_uint2(0u, 0u);
#pragma unroll
            for (int k = 0; k < 4; ++k) {
                a0 += lo16(uu[k].x); a1 += hi16(uu[k].x);
                a2 += lo16(uu[k].y); a3 += hi16(uu[k].y);
            }
            i += 8;
        }
        a0 += __shfl_xor(a0, 32, 64);
        a1 += __shfl_xor(a1, 32, 64);
        a2 += __shfl_xor(a2, 32, 64);
        a3 += __shfl_xor(a3, 32, 64);
        if (half == 0) {
            uint2 o;
            o.x = (unsigned)bbits(a0) | ((unsigned)bbits(a1) << 16);
            o.y = (unsigned)bbits(a2) | ((unsigned)bbits(a3) << 16);
            *reinterpret_cast<uint2*>(mnb + (size_t)n * HID + cl * 4) = o;
        }
    }
}

// ---------------- MFMA edge kernels ----------------
// k_h0m: 1024 threads (16 waves), FULL K=160 / 128 outputs per block.
__global__ void k_h0m(const u16* __restrict__ xb, const int* __restrict__ src,
                      const float* __restrict__ eattr, const float* __restrict__ W1,
                      u16* __restrict__ h0, int E) {
    __shared__ __align__(16) char lds[73728];
    char* bfr = lds;                              // 40 frags (s*8+t) x 1024 B
    char* bounce = lds + 40960;                   // 16 waves x 2048 B
    const int tid = threadIdx.x, l = tid & 63, w = tid >> 6;

    for (int idx = tid; idx < 40 * 64; idx += 1024) {
        int f = idx >> 6, ln = idx & 63;
        int s = f >> 3, t = f & 7;
        int j = t * 16 + (ln & 15);
        int k0 = s * 32 + (ln >> 4) * 8;
        u16 u[8];
#pragma unroll
        for (int i = 0; i < 8; ++i) {
            int k = k0 + i;
            u[i] = (k < FDIM + 1) ? bbits(W1[j * (FDIM + 1) + k]) : (u16)0;
        }
        uint4 v;
        v.x = u[0] | ((unsigned)u[1] << 16);
        v.y = u[2] | ((unsigned)u[3] << 16);
        v.z = u[4] | ((unsigned)u[5] << 16);
        v.w = u[6] | ((unsigned)u[7] << 16);
        *reinterpret_cast<uint4*>(bfr + idx * 16) = v;
    }
    __syncthreads();

    const int arow = l & 15;
    const int k0a = (l >> 4) * 8;
    const int rrow = l >> 3, rch = l & 7;
    const int ntiles = (E + 255) >> 8;
    for (int tile = blockIdx.x; tile < ntiles; tile += gridDim.x) {
        int e0 = tile << 8;
        int e = e0 + w * 16 + arow;
        bool okA = e < E;
        int sn = okA ? src[e] : 0;
        uint4 av[5];
#pragma unroll
        for (int s = 0; s < 5; ++s) {
            int p = s * 32 + k0a;
            av[s] = make_uint4(0, 0, 0, 0);
            if (okA && p < 136) {
                av[s] = *reinterpret_cast<const uint4*>(xb + (size_t)sn * 136 + p);
                if (p == 128)  // inject eattr at k=133 (hi half of .z)
                    av[s].z = (av[s].z & 0xFFFFu) | ((unsigned)bbits(eattr[e]) << 16);
            }
        }
        v4f acc[8];
#pragma unroll
        for (int t = 0; t < 8; ++t) acc[t] = (v4f){0.f, 0.f, 0.f, 0.f};
#pragma unroll
        for (int s = 0; s < 5; ++s) {
            short8 af = *reinterpret_cast<short8*>(&av[s]);
#pragma unroll
            for (int t = 0; t < 8; ++t) {
                short8 bv = *reinterpret_cast<short8*>(bfr + ((s * 8 + t) * 64 + l) * 16);
                acc[t] = __builtin_amdgcn_mfma_f32_16x16x32_bf16(af, bv, acc[t], 0, 0, 0);
            }
        }
        // two-pass bounce (16 rows x 128 B per pass per wave)
        char* wb = bounce + w * 2048;
#pragma unroll
        for (int half = 0; half < 2; ++half) {
#pragma unroll
            for (int tt = 0; tt < 4; ++tt) {
                int t = half * 4 + tt;
#pragma unroll
                for (int r = 0; r < 4; ++r) {
                    int row = (l >> 4) * 4 + r;
                    int cb = (tt * 16 + (l & 15)) * 2;
                    *reinterpret_cast<u16*>(wb + row * 128 + (cb ^ ((row & 7) << 4))) =
                        bbits(fmaxf(acc[t][r], 0.f));
                }
            }
#pragma unroll
            for (int q = 0; q < 2; ++q) {
                int row = rrow + q * 8;
                int off_in = rch * 16;
                uint4 v = *reinterpret_cast<uint4*>(wb + row * 128 + (off_in ^ ((row & 7) << 4)));
                int e2 = e0 + w * 16 + row;
                if (e2 < E)
                    *reinterpret_cast<uint4*>((char*)(h0 + (size_t)e2 * HID) + half * 128 + off_in) = v;
            }
        }
    }
}

// hout[e] = relu(h0[e] + W2*(mnb[src[e]] - hin[e^1])), FULL 128 channels per
// block. Two-pass bounce, 40 KB LDS -> 4 blocks/CU. (Best measured config.)
// hin must NOT alias hout. hout may alias h0: all 4 h0-addend words are read
// before any store.
__global__ void k_updm(const int* __restrict__ src, const u16* __restrict__ mnb,
                       const u16* __restrict__ h0, const u16* hin, u16* hout,
                       const float* __restrict__ W2, int E) {
    __shared__ __align__(16) char lds[40960];
    char* bfr = lds;                              // 32 frags (s*8+t) x 1024 B
    char* bounce = lds + 32768;                   // 4 waves x 2048 B
    const int tid = threadIdx.x, l = tid & 63, w = tid >> 6;

    for (int idx = tid; idx < 32 * 64; idx += 256) {
        int f = idx >> 6, ln = idx & 63;
        int s = f >> 3, t = f & 7;
        int j = t * 16 + (ln & 15);
        int k0 = s * 32 + (ln >> 4) * 8;
        const float* wr = W2 + (size_t)j * HID + k0;
        uint4 v;
        v.x = bbits(wr[0]) | ((unsigned)bbits(wr[1]) << 16);
        v.y = bbits(wr[2]) | ((unsigned)bbits(wr[3]) << 16);
        v.z = bbits(wr[4]) | ((unsigned)bbits(wr[5]) << 16);
        v.w = bbits(wr[6]) | ((unsigned)bbits(wr[7]) << 16);
        *reinterpret_cast<uint4*>(bfr + idx * 16) = v;
    }
    __syncthreads();

    const int arow = l & 15;
    const int k0a = (l >> 4) * 8;
    const int rrow = l >> 3, rch = l & 7;
    const int ntiles = (E + 63) >> 6;
    for (int tile = blockIdx.x; tile < ntiles; tile += gridDim.x) {
        int e0 = tile << 6;
        int e = e0 + w * 16 + arow;
        bool okA = e < E;
        int sn = okA ? src[e] : 0;
        v4f acc[8];
#pragma unroll
        for (int t = 0; t < 8; ++t) acc[t] = (v4f){0.f, 0.f, 0.f, 0.f};
#pragma unroll
        for (int s = 0; s < 4; ++s) {
            int p = s * 32 + k0a;
            uint4 av = make_uint4(0, 0, 0, 0);
            if (okA) {
                uint4 a = *reinterpret_cast<const uint4*>(mnb + (size_t)sn * HID + p);
                uint4 b = *reinterpret_cast<const uint4*>(hin + (size_t)(e ^ 1) * HID + p);
                av.x = pksub(a.x, b.x);
                av.y = pksub(a.y, b.y);
                av.z = pksub(a.z, b.z);
                av.w = pksub(a.w, b.w);
            }
            short8 af = *reinterpret_cast<short8*>(&av);
#pragma unroll
            for (int t = 0; t < 8; ++t) {
                short8 bv = *reinterpret_cast<short8*>(bfr + ((s * 8 + t) * 64 + l) * 16);
                acc[t] = __builtin_amdgcn_mfma_f32_16x16x32_bf16(af, bv, acc[t], 0, 0, 0);
            }
        }
        // prefetch ALL h0 addend words before any store (aliasing safety)
        uint4 hv[4];
#pragma unroll
        for (int p = 0; p < 4; ++p) {
            int row = rrow + (p & 1) * 8;
            int off = (p >> 1) * 128 + rch * 16;
            int e2 = e0 + w * 16 + row;
            hv[p] = (e2 < E)
                ? *reinterpret_cast<const uint4*>((const char*)(h0 + (size_t)e2 * HID) + off)
                : make_uint4(0, 0, 0, 0);
        }
        // two-pass bounce through wave-private LDS (16 rows x 128 B per pass)
        char* wb = bounce + w * 2048;
#pragma unroll
        for (int half = 0; half < 2; ++half) {
#pragma unroll
            for (int tt = 0; tt < 4; ++tt) {
                int t = half * 4 + tt;
#pragma unroll
                for (int r = 0; r < 4; ++r) {
                    int row = (l >> 4) * 4 + r;
                    int cb = (tt * 16 + (l & 15)) * 2;
                    *reinterpret_cast<u16*>(wb + row * 128 + (cb ^ ((row & 7) << 4))) =
                        bbits(acc[t][r]);
                }
            }
#pragma unroll
            for (int q = 0; q < 2; ++q) {
                int row = rrow + q * 8;
                int off_in = rch * 16;
                uint4 v = *reinterpret_cast<uint4*>(wb + row * 128 + (off_in ^ ((row & 7) << 4)));
                int e2 = e0 + w * 16 + row;
                int p = half * 2 + q;
                if (e2 < E) {
                    uint4 o;
                    o.x = paddrelu(v.x, hv[p].x);
                    o.y = paddrelu(v.y, hv[p].y);
                    o.z = paddrelu(v.z, hv[p].z);
                    o.w = paddrelu(v.w, hv[p].w);
                    *reinterpret_cast<uint4*>((char*)(hout + (size_t)e2 * HID) + half * 128 + off_in) = o;
                }
            }
        }
    }
}

// ---------------- MFMA node MLP with FUSED final segment-sum ----------------
// z[n] = [xb[n] || segsum_{e in csr run}(hfin[e])]; na[n] = relu(z*W3'+b3).
// The v_msg chunks are gathered directly from hfin via CSR (fp32 accumulate,
// one bf16 round — numerically identical to the old gather+mnb path).
__global__ void k_nodem(const u16* __restrict__ xb, const u16* __restrict__ hfin,
                        const int* __restrict__ csr, const int* __restrict__ offs,
                        const int* __restrict__ deg,
                        const float* __restrict__ W3, const float* __restrict__ b3,
                        u16* __restrict__ na, int N) {
    __shared__ __align__(16) char lds[53248];
    char* bfr = lds;                              // 36 frags (s*4+t) x 1024 B
    char* bounce = lds + 36864;                   // 8 waves x 2048 B
    const int tid = threadIdx.x, l = tid & 63, w = tid >> 6;
    const int y = blockIdx.y;

    for (int idx = tid; idx < 36 * 64; idx += 512) {
        int f = idx >> 6, ln = idx & 63;
        int s = f >> 2, t = f & 3;
        int j = y * 64 + t * 16 + (ln & 15);
        int k0 = s * 32 + (ln >> 4) * 8;
        const float* wr = W3 + (size_t)j * 261;
        u16 u[8];
#pragma unroll
        for (int i = 0; i < 8; ++i) {
            int p = k0 + i;
            float v = 0.f;
            if (p < FDIM) v = wr[p];
            else if (p >= 136 && p < 264) v = wr[p - 3];
            u[i] = bbits(v);
        }
        uint4 v;
        v.x = u[0] | ((unsigned)u[1] << 16);
        v.y = u[2] | ((unsigned)u[3] << 16);
        v.z = u[4] | ((unsigned)u[5] << 16);
        v.w = u[6] | ((unsigned)u[7] << 16);
        *reinterpret_cast<uint4*>(bfr + idx * 16) = v;
    }
    __syncthreads();

    float b3v[4];
#pragma unroll
    for (int t = 0; t < 4; ++t) b3v[t] = b3[y * 64 + t * 16 + (l & 15)];

    const int arow = l & 15;
    const int k0a = (l >> 4) * 8;
    const int ntiles = (N + 127) >> 7;
    for (int tile = blockIdx.x; tile < ntiles; tile += gridDim.x) {
        int n0 = tile << 7;
        int n_a = n0 + w * 16 + arow;
        bool okA = n_a < N;
        int so = okA ? offs[n_a] : 0;
        int dg = okA ? deg[n_a] : 0;
        uint4 av[9];
#pragma unroll
        for (int s = 0; s < 9; ++s) {
            int p = s * 32 + k0a;
            av[s] = make_uint4(0, 0, 0, 0);
            if (!okA) continue;
            if (p < 136) {
                av[s] = *reinterpret_cast<const uint4*>(xb + (size_t)n_a * 136 + p);
            } else if (p < 264) {
                // fused segment-sum: fp32 accumulate over the CSR run
                int chb = p - 136;                 // channel base (0..120)
                float a0 = 0.f, a1 = 0.f, a2 = 0.f, a3 = 0.f,
                      a4 = 0.f, a5 = 0.f, a6 = 0.f, a7 = 0.f;
                int i = 0;
                while (i < dg) {
                    int ei[4];
                    uint4 uu[4];
#pragma unroll
                    for (int k = 0; k < 4; ++k)
                        ei[k] = (i + k < dg) ? csr[so + i + k] : -1;
#pragma unroll
                    for (int k = 0; k < 4; ++k)
                        uu[k] = (ei[k] >= 0)
                            ? *reinterpret_cast<const uint4*>(hfin + (size_t)ei[k] * HID + chb)
                            : make_uint4(0, 0, 0, 0);
#pragma unroll
                    for (int k = 0; k < 4; ++k) {
                        a0 += lo16(uu[k].x); a1 += hi16(uu[k].x);
                        a2 += lo16(uu[k].y); a3 += hi16(uu[k].y);
                        a4 += lo16(uu[k].z); a5 += hi16(uu[k].z);
                        a6 += lo16(uu[k].w); a7 += hi16(uu[k].w);
                    }
                    i += 4;
                }
                av[s].x = (unsigned)bbits(a0) | ((unsigned)bbits(a1) << 16);
                av[s].y = (unsigned)bbits(a2) | ((unsigned)bbits(a3) << 16);
                av[s].z = (unsigned)bbits(a4) | ((unsigned)bbits(a5) << 16);
                av[s].w = (unsigned)bbits(a6) | ((unsigned)bbits(a7) << 16);
            }
        }
        v4f acc[4];
#pragma unroll
        for (int t = 0; t < 4; ++t) acc[t] = (v4f){0.f, 0.f, 0.f, 0.f};
#pragma unroll
        for (int s = 0; s < 9; ++s) {
            short8 af = *reinterpret_cast<short8*>(&av[s]);
#pragma unroll
            for (int t = 0; t < 4; ++t) {
                short8 bv = *reinterpret_cast<short8*>(bfr + ((s * 4 + t) * 64 + l) * 16);
                acc[t] = __builtin_amdgcn_mfma_f32_16x16x32_bf16(af, bv, acc[t], 0, 0, 0);
            }
        }
        char* wb = bounce + w * 2048;
#pragma unroll
        for (int t = 0; t < 4; ++t)
#pragma unroll
            for (int r = 0; r < 4; ++r) {
                int row = (l >> 4) * 4 + r;
                int cb = (t * 16 + (l & 15)) * 2;
                *reinterpret_cast<u16*>(wb + row * 128 + (cb ^ ((row & 7) << 4))) =
                    bbits(fmaxf(acc[t][r] + b3v[t], 0.f));
            }
#pragma unroll
        for (int p = 0; p < 2; ++p) {
            int row = (l >> 3) + p * 8;
            int ch = l & 7;
            uint4 v = *reinterpret_cast<uint4*>(wb + row * 128 + ((ch * 16) ^ ((row & 7) << 4)));
            int n = n0 + w * 16 + row;
            if (n < N)
                *reinterpret_cast<uint4*>((char*)(na + (size_t)n * HID) + y * 128 + ch * 16) = v;
        }
    }
}

// pooled[g] = mean over rows [starts[g], starts[g+1]) of na  (no atomics)
__global__ void k_pool(const u16* __restrict__ na, const int* __restrict__ starts,
                       float* __restrict__ pooled, int G) {
    __shared__ float red[256];
    const int g = blockIdx.x, tid = threadIdx.x;  // 256 threads
    const int ch = tid & 127, half = tid >> 7;
    int s = starts[g], e = starts[g + 1];
    float acc = 0.f;
    int n = s + half;
    for (; n + 2 < e; n += 4) {
        float v0 = u2f(na[(size_t)n * HID + ch]);
        float v1 = u2f(na[(size_t)(n + 2) * HID + ch]);
        acc += v0 + v1;
    }
    for (; n < e; n += 2) acc += u2f(na[(size_t)n * HID + ch]);
    red[tid] = acc;
    __syncthreads();
    if (half == 0) {
        float v = red[tid] + red[tid + 128];
        float cnt = (float)(e - s);
        pooled[(size_t)g * HID + ch] = v / fmaxf(cnt, 1.f);
    }
}

__global__ void k_out(const float* __restrict__ pooled, const float* __restrict__ Wfc,
                      const float* __restrict__ bfc, float* __restrict__ out, int G) {
    __shared__ float pl[HID];
    const int g = blockIdx.x, tid = threadIdx.x;  // 64 threads
    pl[tid] = pooled[(size_t)g * HID + tid];
    pl[tid + 64] = pooled[(size_t)g * HID + tid + 64];
    __syncthreads();
    float acc = bfc[tid];
#pragma unroll
    for (int k = 0; k < HID; ++k) acc += Wfc[tid * HID + k] * pl[k];
    out[(size_t)g * 64 + tid] = tanhf(acc);
}

extern "C" void kernel_launch(void* const* d_in, const int* in_sizes, int n_in,
                              void* d_out, int out_size, void* d_ws, size_t ws_size,
                              hipStream_t stream) {
    const float* x     = (const float*)d_in[0];
    const int*   ei    = (const int*)d_in[1];
    const float* eattr = (const float*)d_in[3];
    const int*   batch = (const int*)d_in[4];
    const float* W1    = (const float*)d_in[6];
    const float* W2    = (const float*)d_in[7];
    const float* W3    = (const float*)d_in[8];
    const float* b3    = (const float*)d_in[9];
    const float* Wfc   = (const float*)d_in[10];
    const float* bfc   = (const float*)d_in[11];
    float* out = (float*)d_out;
    (void)n_in; (void)ws_size;

    const int N = in_sizes[0] / FDIM;
    const int E = in_sizes[3];
    const int G = out_size / 64;
    const int* src = ei;
    const int* dst = ei + E;

    char* ws = (char*)d_ws;
    size_t o = 0;
    u16* h   = (u16*)(ws + o); o += (size_t)E * HID * 2;   // reused as na at the end
    u16* h0  = (u16*)(ws + o); o += (size_t)E * HID * 2;   // holds final h after updm#2
    u16* xb  = (u16*)(ws + o); o += (size_t)N * 136 * 2;
    u16* mnb = (u16*)(ws + o); o += (size_t)N * HID * 2;
    float* pooled = (float*)(ws + o); o += (size_t)G * HID * 4;
    int* starts = (int*)(ws + o); o += (size_t)(G + 1) * 4;
    size_t o_zero = o;
    int* deg    = (int*)(ws + o); o += (size_t)N * 4;
    int* cursor = (int*)(ws + o); o += (size_t)N * 4;
    size_t zero_n = (o - o_zero) / 4;
    int* offs   = (int*)(ws + o); o += (size_t)N * 4;
    int* csr    = (int*)(ws + o); o += (size_t)E * 4;
    int* bsum   = (int*)(ws + o); o += 256 * 4;
    u16* na = h;    // h's last read is updm#2 (hin); k_nodem runs after updm#2

    const int eGrid = (E + 255) / 256;
    const int nGrid = (N + 255) / 256;
    const int nbScan = (N + 1023) / 1024;

    k_zero<<<512, 256, 0, stream>>>((float*)(ws + o_zero), (long long)zero_n);
    k_cast<<<2048, 256, 0, stream>>>(x, xb, N);

    k_hist<<<eGrid, 256, 0, stream>>>(dst, deg, E);
    k_scanA<<<nbScan, 256, 0, stream>>>(deg, offs, bsum, N);
    k_scanB<<<1, 256, 0, stream>>>(bsum, nbScan);
    k_scanC<<<nGrid, 256, 0, stream>>>(offs, bsum, N);
    k_fill<<<eGrid, 256, 0, stream>>>(dst, offs, cursor, csr, E);
    k_starts<<<(G + 256) / 256, 256, 0, stream>>>(batch, starts, N, G);

    // h0 = relu(W1*[x[src],eattr])   (16-wave blocks, single xb fetch)
    k_h0m<<<512, 1024, 0, stream>>>(xb, src, eattr, W1, h0, E);

    // iter 1: gather from h0; update reads h0 (hin + addend), writes h
    k_gather<<<2048, 256, 0, stream>>>(h0, csr, offs, deg, mnb, N);
    k_updm<<<1024, 256, 0, stream>>>(src, mnb, h0, h0, h, W2, E);

    // iter 2: gather from h; update reads h (hin) + h0 (addend), writes h0
    k_gather<<<2048, 256, 0, stream>>>(h, csr, offs, deg, mnb, N);
    k_updm<<<1024, 256, 0, stream>>>(src, mnb, h0, h, h0, W2, E);

    // node MLP with fused final segment-sum (reads h0 = final h directly)
    k_nodem<<<dim3(256, 2), 512, 0, stream>>>(xb, h0, csr, offs, deg, W3, b3, na, N);
    k_pool<<<G, 256, 0, stream>>>(na, starts, pooled, G);
    k_out<<<G, 64, 0, stream>>>(pooled, Wfc, bfc, out, G);
}

// Round 17
// 404.283 us; speedup vs baseline: 1.1021x; 1.1021x over previous
//
#include <hip/hip_runtime.h>
#include <hip/hip_bf16.h>

#define HID 128
#define FDIM 133

typedef __hip_bfloat16 bf16;
typedef unsigned short u16;
typedef __attribute__((ext_vector_type(8))) short short8;
typedef __attribute__((ext_vector_type(4))) float v4f;

__device__ __forceinline__ u16 bbits(float v) {
    union { bf16 b; u16 u; } cv; cv.b = __float2bfloat16(v); return cv.u;
}
__device__ __forceinline__ float lo16(unsigned u) { return __uint_as_float(u << 16); }
__device__ __forceinline__ float hi16(unsigned u) { return __uint_as_float(u & 0xffff0000u); }
__device__ __forceinline__ float u2f(u16 u) { return __uint_as_float((unsigned)u << 16); }
__device__ __forceinline__ unsigned pksub(unsigned a, unsigned b) {
    float lo = lo16(a) - lo16(b);
    float hi = hi16(a) - hi16(b);
    return (unsigned)bbits(lo) | ((unsigned)bbits(hi) << 16);
}
__device__ __forceinline__ unsigned paddrelu(unsigned a, unsigned b) {
    float lo = fmaxf(lo16(a) + lo16(b), 0.f);
    float hi = fmaxf(hi16(a) + hi16(b), 0.f);
    return (unsigned)bbits(lo) | ((unsigned)bbits(hi) << 16);
}

__global__ void k_zero(float* __restrict__ p, long long n) {
    long long i = (long long)blockIdx.x * blockDim.x + threadIdx.x;
    long long st = (long long)gridDim.x * blockDim.x;
    for (; i < n; i += st) p[i] = 0.f;
}

// xb[n][136] = bf16(x[n][0..132]), 0 pad for 133..135
__global__ void k_cast(const float* __restrict__ x, u16* __restrict__ xb, int N) {
    int i = blockIdx.x * blockDim.x + threadIdx.x;
    int st = gridDim.x * blockDim.x;
    int total = N * 136;
    for (; i < total; i += st) {
        int n = i / 136, k = i - n * 136;
        float v = (k < FDIM) ? x[(size_t)n * FDIM + k] : 0.f;
        xb[i] = bbits(v);
    }
}

// ---------------- CSR build (incoming edges per dst) ----------------
__global__ void k_hist(const int* __restrict__ dst, int* __restrict__ deg, int E) {
    int i = blockIdx.x * blockDim.x + threadIdx.x;
    if (i < E) atomicAdd(&deg[dst[i]], 1);
}

__global__ void k_scanA(const int* __restrict__ deg, int* __restrict__ offs,
                        int* __restrict__ bsum, int N) {
    __shared__ int sh[256];
    int t = threadIdx.x;
    int base = blockIdx.x * 1024 + t * 4;
    int d0 = (base + 0 < N) ? deg[base + 0] : 0;
    int d1 = (base + 1 < N) ? deg[base + 1] : 0;
    int d2 = (base + 2 < N) ? deg[base + 2] : 0;
    int d3 = (base + 3 < N) ? deg[base + 3] : 0;
    sh[t] = d0 + d1 + d2 + d3;
    __syncthreads();
    for (int off = 1; off < 256; off <<= 1) {
        int v = (t >= off) ? sh[t - off] : 0;
        __syncthreads();
        sh[t] += v;
        __syncthreads();
    }
    int o = (t > 0) ? sh[t - 1] : 0;
    if (t == 255) bsum[blockIdx.x] = sh[255];
    if (base + 0 < N) offs[base + 0] = o; o += d0;
    if (base + 1 < N) offs[base + 1] = o; o += d1;
    if (base + 2 < N) offs[base + 2] = o; o += d2;
    if (base + 3 < N) offs[base + 3] = o;
}

__global__ void k_scanB(int* __restrict__ bsum, int nb) {
    __shared__ int sh[256];
    int t = threadIdx.x;
    sh[t] = (t < nb) ? bsum[t] : 0;
    __syncthreads();
    for (int off = 1; off < 256; off <<= 1) {
        int v = (t >= off) ? sh[t - off] : 0;
        __syncthreads();
        sh[t] += v;
        __syncthreads();
    }
    if (t < nb) bsum[t] = (t > 0) ? sh[t - 1] : 0;
}

__global__ void k_scanC(int* __restrict__ offs, const int* __restrict__ bsum, int N) {
    int i = blockIdx.x * blockDim.x + threadIdx.x;
    if (i < N) offs[i] += bsum[i >> 10];
}

__global__ void k_fill(const int* __restrict__ dst, const int* __restrict__ offs,
                       int* __restrict__ cursor, int* __restrict__ csr, int E) {
    int e = blockIdx.x * blockDim.x + threadIdx.x;
    if (e < E) {
        int d = dst[e];
        int p = offs[d] + atomicAdd(&cursor[d], 1);
        csr[p] = e;
    }
}

// starts[g] = lower_bound(batch, g) for g in [0, G]  (batch sorted)
__global__ void k_starts(const int* __restrict__ batch, int* __restrict__ starts,
                         int N, int G) {
    int g = blockIdx.x * blockDim.x + threadIdx.x;
    if (g > G) return;
    int lo = 0, hi = N;
    while (lo < hi) { int mid = (lo + hi) >> 1; if (batch[mid] < g) lo = mid + 1; else hi = mid; }
    starts[g] = lo;
}

// mnb[n] (bf16) = sum of h rows over incoming edges.
// Half-wave pairing: lanes 0-31 even-slot edges, lanes 32-63 odd-slot; each
// lane loads uint2 (8 B = 4 channels). Cross-half combine via shfl_xor.
__global__ void k_gather(const u16* __restrict__ h, const int* __restrict__ csr,
                         const int* __restrict__ offs, const int* __restrict__ deg,
                         u16* __restrict__ mnb, int N) {
    int gw = (blockIdx.x * blockDim.x + threadIdx.x) >> 6;
    int lane = threadIdx.x & 63;
    int nw = (gridDim.x * blockDim.x) >> 6;
    const int half = lane >> 5;
    const int cl = lane & 31;
    for (int n = gw; n < N; n += nw) {
        int s = offs[n], d = deg[n];
        float a0 = 0.f, a1 = 0.f, a2 = 0.f, a3 = 0.f;
        int i = 0;
        while (i < d) {
            int ei[4];
            uint2 uu[4];
#pragma unroll
            for (int k = 0; k < 4; ++k) {
                int j = i + 2 * k + half;
                ei[k] = (j < d) ? csr[s + j] : -1;
            }
#pragma unroll
            for (int k = 0; k < 4; ++k)
                uu[k] = (ei[k] >= 0)
                    ? *reinterpret_cast<const uint2*>(h + (size_t)ei[k] * HID + cl * 4)
                    : make_uint2(0u, 0u);
#pragma unroll
            for (int k = 0; k < 4; ++k) {
                a0 += lo16(uu[k].x); a1 += hi16(uu[k].x);
                a2 += lo16(uu[k].y); a3 += hi16(uu[k].y);
            }
            i += 8;
        }
        a0 += __shfl_xor(a0, 32, 64);
        a1 += __shfl_xor(a1, 32, 64);
        a2 += __shfl_xor(a2, 32, 64);
        a3 += __shfl_xor(a3, 32, 64);
        if (half == 0) {
            uint2 o;
            o.x = (unsigned)bbits(a0) | ((unsigned)bbits(a1) << 16);
            o.y = (unsigned)bbits(a2) | ((unsigned)bbits(a3) << 16);
            *reinterpret_cast<uint2*>(mnb + (size_t)n * HID + cl * 4) = o;
        }
    }
}

// ---------------- MFMA edge kernels ----------------
// k_h0m: 1024 threads (16 waves), FULL K=160 / 128 outputs per block.
__global__ void k_h0m(const u16* __restrict__ xb, const int* __restrict__ src,
                      const float* __restrict__ eattr, const float* __restrict__ W1,
                      u16* __restrict__ h0, int E) {
    __shared__ __align__(16) char lds[73728];
    char* bfr = lds;                              // 40 frags (s*8+t) x 1024 B
    char* bounce = lds + 40960;                   // 16 waves x 2048 B
    const int tid = threadIdx.x, l = tid & 63, w = tid >> 6;

    for (int idx = tid; idx < 40 * 64; idx += 1024) {
        int f = idx >> 6, ln = idx & 63;
        int s = f >> 3, t = f & 7;
        int j = t * 16 + (ln & 15);
        int k0 = s * 32 + (ln >> 4) * 8;
        u16 u[8];
#pragma unroll
        for (int i = 0; i < 8; ++i) {
            int k = k0 + i;
            u[i] = (k < FDIM + 1) ? bbits(W1[j * (FDIM + 1) + k]) : (u16)0;
        }
        uint4 v;
        v.x = u[0] | ((unsigned)u[1] << 16);
        v.y = u[2] | ((unsigned)u[3] << 16);
        v.z = u[4] | ((unsigned)u[5] << 16);
        v.w = u[6] | ((unsigned)u[7] << 16);
        *reinterpret_cast<uint4*>(bfr + idx * 16) = v;
    }
    __syncthreads();

    const int arow = l & 15;
    const int k0a = (l >> 4) * 8;
    const int rrow = l >> 3, rch = l & 7;
    const int ntiles = (E + 255) >> 8;
    for (int tile = blockIdx.x; tile < ntiles; tile += gridDim.x) {
        int e0 = tile << 8;
        int e = e0 + w * 16 + arow;
        bool okA = e < E;
        int sn = okA ? src[e] : 0;
        uint4 av[5];
#pragma unroll
        for (int s = 0; s < 5; ++s) {
            int p = s * 32 + k0a;
            av[s] = make_uint4(0, 0, 0, 0);
            if (okA && p < 136) {
                av[s] = *reinterpret_cast<const uint4*>(xb + (size_t)sn * 136 + p);
                if (p == 128)  // inject eattr at k=133 (hi half of .z)
                    av[s].z = (av[s].z & 0xFFFFu) | ((unsigned)bbits(eattr[e]) << 16);
            }
        }
        v4f acc[8];
#pragma unroll
        for (int t = 0; t < 8; ++t) acc[t] = (v4f){0.f, 0.f, 0.f, 0.f};
#pragma unroll
        for (int s = 0; s < 5; ++s) {
            short8 af = *reinterpret_cast<short8*>(&av[s]);
#pragma unroll
            for (int t = 0; t < 8; ++t) {
                short8 bv = *reinterpret_cast<short8*>(bfr + ((s * 8 + t) * 64 + l) * 16);
                acc[t] = __builtin_amdgcn_mfma_f32_16x16x32_bf16(af, bv, acc[t], 0, 0, 0);
            }
        }
        // two-pass bounce (16 rows x 128 B per pass per wave)
        char* wb = bounce + w * 2048;
#pragma unroll
        for (int half = 0; half < 2; ++half) {
#pragma unroll
            for (int tt = 0; tt < 4; ++tt) {
                int t = half * 4 + tt;
#pragma unroll
                for (int r = 0; r < 4; ++r) {
                    int row = (l >> 4) * 4 + r;
                    int cb = (tt * 16 + (l & 15)) * 2;
                    *reinterpret_cast<u16*>(wb + row * 128 + (cb ^ ((row & 7) << 4))) =
                        bbits(fmaxf(acc[t][r], 0.f));
                }
            }
#pragma unroll
            for (int q = 0; q < 2; ++q) {
                int row = rrow + q * 8;
                int off_in = rch * 16;
                uint4 v = *reinterpret_cast<uint4*>(wb + row * 128 + (off_in ^ ((row & 7) << 4)));
                int e2 = e0 + w * 16 + row;
                if (e2 < E)
                    *reinterpret_cast<uint4*>((char*)(h0 + (size_t)e2 * HID) + half * 128 + off_in) = v;
            }
        }
    }
}

// hout[e] = relu(h0[e] + W2*(mnb[src[e]] - hin[e^1])), FULL 128 channels per
// block. Two-pass bounce, 40 KB LDS -> 4 blocks/CU. (Best measured config.)
// hin must NOT alias hout. hout may alias h0: all 4 h0-addend words are read
// before any store.
__global__ void k_updm(const int* __restrict__ src, const u16* __restrict__ mnb,
                       const u16* __restrict__ h0, const u16* hin, u16* hout,
                       const float* __restrict__ W2, int E) {
    __shared__ __align__(16) char lds[40960];
    char* bfr = lds;                              // 32 frags (s*8+t) x 1024 B
    char* bounce = lds + 32768;                   // 4 waves x 2048 B
    const int tid = threadIdx.x, l = tid & 63, w = tid >> 6;

    for (int idx = tid; idx < 32 * 64; idx += 256) {
        int f = idx >> 6, ln = idx & 63;
        int s = f >> 3, t = f & 7;
        int j = t * 16 + (ln & 15);
        int k0 = s * 32 + (ln >> 4) * 8;
        const float* wr = W2 + (size_t)j * HID + k0;
        uint4 v;
        v.x = bbits(wr[0]) | ((unsigned)bbits(wr[1]) << 16);
        v.y = bbits(wr[2]) | ((unsigned)bbits(wr[3]) << 16);
        v.z = bbits(wr[4]) | ((unsigned)bbits(wr[5]) << 16);
        v.w = bbits(wr[6]) | ((unsigned)bbits(wr[7]) << 16);
        *reinterpret_cast<uint4*>(bfr + idx * 16) = v;
    }
    __syncthreads();

    const int arow = l & 15;
    const int k0a = (l >> 4) * 8;
    const int rrow = l >> 3, rch = l & 7;
    const int ntiles = (E + 63) >> 6;
    for (int tile = blockIdx.x; tile < ntiles; tile += gridDim.x) {
        int e0 = tile << 6;
        int e = e0 + w * 16 + arow;
        bool okA = e < E;
        int sn = okA ? src[e] : 0;
        v4f acc[8];
#pragma unroll
        for (int t = 0; t < 8; ++t) acc[t] = (v4f){0.f, 0.f, 0.f, 0.f};
#pragma unroll
        for (int s = 0; s < 4; ++s) {
            int p = s * 32 + k0a;
            uint4 av = make_uint4(0, 0, 0, 0);
            if (okA) {
                uint4 a = *reinterpret_cast<const uint4*>(mnb + (size_t)sn * HID + p);
                uint4 b = *reinterpret_cast<const uint4*>(hin + (size_t)(e ^ 1) * HID + p);
                av.x = pksub(a.x, b.x);
                av.y = pksub(a.y, b.y);
                av.z = pksub(a.z, b.z);
                av.w = pksub(a.w, b.w);
            }
            short8 af = *reinterpret_cast<short8*>(&av);
#pragma unroll
            for (int t = 0; t < 8; ++t) {
                short8 bv = *reinterpret_cast<short8*>(bfr + ((s * 8 + t) * 64 + l) * 16);
                acc[t] = __builtin_amdgcn_mfma_f32_16x16x32_bf16(af, bv, acc[t], 0, 0, 0);
            }
        }
        // prefetch ALL h0 addend words before any store (aliasing safety)
        uint4 hv[4];
#pragma unroll
        for (int p = 0; p < 4; ++p) {
            int row = rrow + (p & 1) * 8;
            int off = (p >> 1) * 128 + rch * 16;
            int e2 = e0 + w * 16 + row;
            hv[p] = (e2 < E)
                ? *reinterpret_cast<const uint4*>((const char*)(h0 + (size_t)e2 * HID) + off)
                : make_uint4(0, 0, 0, 0);
        }
        // two-pass bounce through wave-private LDS (16 rows x 128 B per pass)
        char* wb = bounce + w * 2048;
#pragma unroll
        for (int half = 0; half < 2; ++half) {
#pragma unroll
            for (int tt = 0; tt < 4; ++tt) {
                int t = half * 4 + tt;
#pragma unroll
                for (int r = 0; r < 4; ++r) {
                    int row = (l >> 4) * 4 + r;
                    int cb = (tt * 16 + (l & 15)) * 2;
                    *reinterpret_cast<u16*>(wb + row * 128 + (cb ^ ((row & 7) << 4))) =
                        bbits(acc[t][r]);
                }
            }
#pragma unroll
            for (int q = 0; q < 2; ++q) {
                int row = rrow + q * 8;
                int off_in = rch * 16;
                uint4 v = *reinterpret_cast<uint4*>(wb + row * 128 + (off_in ^ ((row & 7) << 4)));
                int e2 = e0 + w * 16 + row;
                int p = half * 2 + q;
                if (e2 < E) {
                    uint4 o;
                    o.x = paddrelu(v.x, hv[p].x);
                    o.y = paddrelu(v.y, hv[p].y);
                    o.z = paddrelu(v.z, hv[p].z);
                    o.w = paddrelu(v.w, hv[p].w);
                    *reinterpret_cast<uint4*>((char*)(hout + (size_t)e2 * HID) + half * 128 + off_in) = o;
                }
            }
        }
    }
}

// ---------------- MFMA node MLP -> bf16 node_attr (no atomics) ----------------
// 512 threads (8 waves), y-split halves. LDS 36 KB weights + 16 KB bounce.
__global__ void k_nodem(const u16* __restrict__ xb, const u16* __restrict__ mnb,
                        const float* __restrict__ W3, const float* __restrict__ b3,
                        u16* __restrict__ na, int N) {
    __shared__ __align__(16) char lds[53248];
    char* bfr = lds;                              // 36 frags (s*4+t) x 1024 B
    char* bounce = lds + 36864;                   // 8 waves x 2048 B
    const int tid = threadIdx.x, l = tid & 63, w = tid >> 6;
    const int y = blockIdx.y;

    for (int idx = tid; idx < 36 * 64; idx += 512) {
        int f = idx >> 6, ln = idx & 63;
        int s = f >> 2, t = f & 3;
        int j = y * 64 + t * 16 + (ln & 15);
        int k0 = s * 32 + (ln >> 4) * 8;
        const float* wr = W3 + (size_t)j * 261;
        u16 u[8];
#pragma unroll
        for (int i = 0; i < 8; ++i) {
            int p = k0 + i;
            float v = 0.f;
            if (p < FDIM) v = wr[p];
            else if (p >= 136 && p < 264) v = wr[p - 3];
            u[i] = bbits(v);
        }
        uint4 v;
        v.x = u[0] | ((unsigned)u[1] << 16);
        v.y = u[2] | ((unsigned)u[3] << 16);
        v.z = u[4] | ((unsigned)u[5] << 16);
        v.w = u[6] | ((unsigned)u[7] << 16);
        *reinterpret_cast<uint4*>(bfr + idx * 16) = v;
    }
    __syncthreads();

    float b3v[4];
#pragma unroll
    for (int t = 0; t < 4; ++t) b3v[t] = b3[y * 64 + t * 16 + (l & 15)];

    const int arow = l & 15;
    const int k0a = (l >> 4) * 8;
    const int ntiles = (N + 127) >> 7;
    for (int tile = blockIdx.x; tile < ntiles; tile += gridDim.x) {
        int n0 = tile << 7;
        int n_a = n0 + w * 16 + arow;
        bool okA = n_a < N;
        uint4 av[9];
#pragma unroll
        for (int s = 0; s < 9; ++s) {
            int p = s * 32 + k0a;
            av[s] = make_uint4(0, 0, 0, 0);
            if (okA) {
                if (p < 136)       av[s] = *reinterpret_cast<const uint4*>(xb + (size_t)n_a * 136 + p);
                else if (p < 264)  av[s] = *reinterpret_cast<const uint4*>(mnb + (size_t)n_a * HID + (p - 136));
            }
        }
        v4f acc[4];
#pragma unroll
        for (int t = 0; t < 4; ++t) acc[t] = (v4f){0.f, 0.f, 0.f, 0.f};
#pragma unroll
        for (int s = 0; s < 9; ++s) {
            short8 af = *reinterpret_cast<short8*>(&av[s]);
#pragma unroll
            for (int t = 0; t < 4; ++t) {
                short8 bv = *reinterpret_cast<short8*>(bfr + ((s * 4 + t) * 64 + l) * 16);
                acc[t] = __builtin_amdgcn_mfma_f32_16x16x32_bf16(af, bv, acc[t], 0, 0, 0);
            }
        }
        char* wb = bounce + w * 2048;
#pragma unroll
        for (int t = 0; t < 4; ++t)
#pragma unroll
            for (int r = 0; r < 4; ++r) {
                int row = (l >> 4) * 4 + r;
                int cb = (t * 16 + (l & 15)) * 2;
                *reinterpret_cast<u16*>(wb + row * 128 + (cb ^ ((row & 7) << 4))) =
                    bbits(fmaxf(acc[t][r] + b3v[t], 0.f));
            }
#pragma unroll
        for (int p = 0; p < 2; ++p) {
            int row = (l >> 3) + p * 8;
            int ch = l & 7;
            uint4 v = *reinterpret_cast<uint4*>(wb + row * 128 + ((ch * 16) ^ ((row & 7) << 4)));
            int n = n0 + w * 16 + row;
            if (n < N)
                *reinterpret_cast<uint4*>((char*)(na + (size_t)n * HID) + y * 128 + ch * 16) = v;
        }
    }
}

// pooled[g] = mean over rows [starts[g], starts[g+1]) of na  (no atomics)
__global__ void k_pool(const u16* __restrict__ na, const int* __restrict__ starts,
                       float* __restrict__ pooled, int G) {
    __shared__ float red[256];
    const int g = blockIdx.x, tid = threadIdx.x;  // 256 threads
    const int ch = tid & 127, half = tid >> 7;
    int s = starts[g], e = starts[g + 1];
    float acc = 0.f;
    int n = s + half;
    for (; n + 2 < e; n += 4) {
        float v0 = u2f(na[(size_t)n * HID + ch]);
        float v1 = u2f(na[(size_t)(n + 2) * HID + ch]);
        acc += v0 + v1;
    }
    for (; n < e; n += 2) acc += u2f(na[(size_t)n * HID + ch]);
    red[tid] = acc;
    __syncthreads();
    if (half == 0) {
        float v = red[tid] + red[tid + 128];
        float cnt = (float)(e - s);
        pooled[(size_t)g * HID + ch] = v / fmaxf(cnt, 1.f);
    }
}

__global__ void k_out(const float* __restrict__ pooled, const float* __restrict__ Wfc,
                      const float* __restrict__ bfc, float* __restrict__ out, int G) {
    __shared__ float pl[HID];
    const int g = blockIdx.x, tid = threadIdx.x;  // 64 threads
    pl[tid] = pooled[(size_t)g * HID + tid];
    pl[tid + 64] = pooled[(size_t)g * HID + tid + 64];
    __syncthreads();
    float acc = bfc[tid];
#pragma unroll
    for (int k = 0; k < HID; ++k) acc += Wfc[tid * HID + k] * pl[k];
    out[(size_t)g * 64 + tid] = tanhf(acc);
}

extern "C" void kernel_launch(void* const* d_in, const int* in_sizes, int n_in,
                              void* d_out, int out_size, void* d_ws, size_t ws_size,
                              hipStream_t stream) {
    const float* x     = (const float*)d_in[0];
    const int*   ei    = (const int*)d_in[1];
    const float* eattr = (const float*)d_in[3];
    const int*   batch = (const int*)d_in[4];
    const float* W1    = (const float*)d_in[6];
    const float* W2    = (const float*)d_in[7];
    const float* W3    = (const float*)d_in[8];
    const float* b3    = (const float*)d_in[9];
    const float* Wfc   = (const float*)d_in[10];
    const float* bfc   = (const float*)d_in[11];
    float* out = (float*)d_out;
    (void)n_in; (void)ws_size;

    const int N = in_sizes[0] / FDIM;
    const int E = in_sizes[3];
    const int G = out_size / 64;
    const int* src = ei;
    const int* dst = ei + E;

    char* ws = (char*)d_ws;
    size_t o = 0;
    u16* h   = (u16*)(ws + o); o += (size_t)E * HID * 2;   // reused as na at the end
    u16* h0  = (u16*)(ws + o); o += (size_t)E * HID * 2;   // holds final h after updm#2
    u16* xb  = (u16*)(ws + o); o += (size_t)N * 136 * 2;
    u16* mnb = (u16*)(ws + o); o += (size_t)N * HID * 2;
    float* pooled = (float*)(ws + o); o += (size_t)G * HID * 4;
    int* starts = (int*)(ws + o); o += (size_t)(G + 1) * 4;
    size_t o_zero = o;
    int* deg    = (int*)(ws + o); o += (size_t)N * 4;
    int* cursor = (int*)(ws + o); o += (size_t)N * 4;
    size_t zero_n = (o - o_zero) / 4;
    int* offs   = (int*)(ws + o); o += (size_t)N * 4;
    int* csr    = (int*)(ws + o); o += (size_t)E * 4;
    int* bsum   = (int*)(ws + o); o += 256 * 4;
    u16* na = h;    // h's last read is updm#2 (hin); k_nodem runs after gather#3

    const int eGrid = (E + 255) / 256;
    const int nGrid = (N + 255) / 256;
    const int nbScan = (N + 1023) / 1024;

    k_zero<<<512, 256, 0, stream>>>((float*)(ws + o_zero), (long long)zero_n);
    k_cast<<<2048, 256, 0, stream>>>(x, xb, N);

    k_hist<<<eGrid, 256, 0, stream>>>(dst, deg, E);
    k_scanA<<<nbScan, 256, 0, stream>>>(deg, offs, bsum, N);
    k_scanB<<<1, 256, 0, stream>>>(bsum, nbScan);
    k_scanC<<<nGrid, 256, 0, stream>>>(offs, bsum, N);
    k_fill<<<eGrid, 256, 0, stream>>>(dst, offs, cursor, csr, E);
    k_starts<<<(G + 256) / 256, 256, 0, stream>>>(batch, starts, N, G);

    // h0 = relu(W1*[x[src],eattr])   (16-wave blocks, single xb fetch)
    k_h0m<<<512, 1024, 0, stream>>>(xb, src, eattr, W1, h0, E);

    // iter 1: gather from h0; update reads h0 (hin + addend), writes h
    k_gather<<<2048, 256, 0, stream>>>(h0, csr, offs, deg, mnb, N);
    k_updm<<<1024, 256, 0, stream>>>(src, mnb, h0, h0, h, W2, E);

    // iter 2: gather from h; update reads h (hin) + h0 (addend), writes h0
    k_gather<<<2048, 256, 0, stream>>>(h, csr, offs, deg, mnb, N);
    k_updm<<<1024, 256, 0, stream>>>(src, mnb, h0, h, h0, W2, E);

    // final v_msg from h0 (which now holds the final h)
    k_gather<<<2048, 256, 0, stream>>>(h0, csr, offs, deg, mnb, N);

    // node MLP -> na (= h buffer, dead), then atomic-free pooling and readout
    k_nodem<<<dim3(256, 2), 512, 0, stream>>>(xb, mnb, W3, b3, na, N);
    k_pool<<<G, 256, 0, stream>>>(na, starts, pooled, G);
    k_out<<<G, 64, 0, stream>>>(pooled, Wfc, bfc, out, G);
}